// Round 1
// baseline (2375.207 us; speedup 1.0000x reference)
//
#include <hip/hip_runtime.h>
#include <hip/hip_fp16.h>
#include <stdint.h>

typedef _Float16 f16;
typedef _Float16 f16x4 __attribute__((ext_vector_type(4)));
typedef _Float16 f16x8 __attribute__((ext_vector_type(8)));
typedef float f32x4 __attribute__((ext_vector_type(4)));
typedef unsigned long long u64;

#define N_TOK 8192
#define VOCAB 8192
#define DIM   4096
#define KPACK 8192   // fp16 elems per packed row: [hi(4096) | lo(4096)]

// ---------------------------------------------------------------------------
// async global->LDS, 16B per lane (LDS dest is wave-uniform base + lane*16)
__device__ __forceinline__ void gload16(const f16* g, void* l) {
    __builtin_amdgcn_global_load_lds(
        (const __attribute__((address_space(1))) unsigned int*)(uintptr_t)g,
        (__attribute__((address_space(3))) unsigned int*)(uintptr_t)l,
        16, 0, 0);
}

// ---------------------------------------------------------------------------
// K_pack: split f32 rows into fp16 (hi,lo) packed operands; e-norms (f64 acc);
// init argmin slots + counts.
__global__ __launch_bounds__(256) void k_pack(const float* __restrict__ inputs,
                                              const float* __restrict__ embedding,
                                              f16* __restrict__ apk, f16* __restrict__ bpk,
                                              float* __restrict__ enorms,
                                              u64* __restrict__ slots,
                                              int* __restrict__ counts) {
    int b = blockIdx.x, t = threadIdx.x;
    bool isB = b >= N_TOK;
    int row = isB ? b - N_TOK : b;
    const float* src = (isB ? embedding : inputs) + (size_t)row * DIM;
    f16* dst = (isB ? bpk : apk) + (size_t)row * KPACK;
    double nrm = 0.0;
#pragma unroll
    for (int k = 0; k < 4; k++) {
        int d0 = t * 4 + 1024 * k;
        float4 v = *(const float4*)(src + d0);
        float xs[4] = {v.x, v.y, v.z, v.w};
        f16x4 hv, lv;
#pragma unroll
        for (int u = 0; u < 4; u++) {
            float x = xs[u];
            f16 h = (f16)x;
            hv[u] = h;
            lv[u] = (f16)(x - (float)h);
            nrm += (double)x * (double)x;
        }
        *(f16x4*)(dst + d0) = hv;
        *(f16x4*)(dst + DIM + d0) = lv;
    }
    if (isB) {
        __shared__ double red[256];
        red[t] = nrm;
        __syncthreads();
        for (int off = 128; off > 0; off >>= 1) {
            if (t < off) red[t] += red[t + off];
            __syncthreads();
        }
        if (t == 0) {
            enorms[row] = (float)red[0];
            slots[row] = 0xFFFFFFFFFFFFFFFFULL;
            counts[row] = 0;
        }
    }
}

// ---------------------------------------------------------------------------
// K_gemm: S = x·e via 3-term fp16 split MFMA; fused argmin epilogue.
// 128x128 tile, BK=64 original-k, 4 waves (2x2), per-wave 64x64 (4x4 frags).
// LDS: Ahi|Alo|Bhi|Blo tiles, each [128 rows][64 k] fp16 with XOR-16B swizzle
// realized by pre-swizzling the global source (global_load_lds dest is linear).
__global__ __launch_bounds__(256) void k_gemm(const f16* __restrict__ apk,
                                              const f16* __restrict__ bpk,
                                              const float* __restrict__ enorms,
                                              u64* __restrict__ slots) {
    __shared__ alignas(16) char lds[65536];
    int wg = blockIdx.x;
    wg = (wg & 7) * 512 + (wg >> 3);      // XCD swizzle (4096 % 8 == 0 -> bijective)
    int bm = wg >> 6, bn = wg & 63;
    int tid = threadIdx.x;
    int lane = tid & 63, wid = tid >> 6;
    int wm = wid >> 1, wn = wid & 1;

    // staging descriptors: 16 wave-issues: tile = e>>2 (Ahi,Alo,Bhi,Blo), q = e&3
    const f16* srcs[16];
    unsigned ldsoff[16];
#pragma unroll
    for (int e = 0; e < 16; e++) {
        int tile = e >> 2, q = e & 3;
        int s = (q * 4 + wid) * 64 + lane;   // 16B slot index within tile
        int r = s >> 3;                      // row 0..127
        int c8 = (s & 7) ^ (r & 7);          // inverse swizzle on source
        int isB = tile >> 1, seg = tile & 1;
        int row = (isB ? bn : bm) * 128 + r;
        srcs[e] = (isB ? bpk : apk) + (size_t)row * KPACK + seg * DIM + c8 * 8;
        ldsoff[e] = tile * 16384 + (q * 4 + wid) * 1024;
    }

    f32x4 acc[4][4];
#pragma unroll
    for (int m = 0; m < 4; m++)
#pragma unroll
        for (int n = 0; n < 4; n++) acc[m][n] = (f32x4){0.f, 0.f, 0.f, 0.f};

    for (int kt = 0; kt < DIM / 64; ++kt) {
#pragma unroll
        for (int e = 0; e < 16; e++) gload16(srcs[e] + kt * 64, &lds[ldsoff[e]]);
        __syncthreads();   // drains vmcnt -> LDS tiles ready
#pragma unroll
        for (int kk = 0; kk < 2; kk++) {
            f16x8 ah[4], al[4], bh[4], bl[4];
            int cb = kk * 64 + (lane >> 4) * 16;
#pragma unroll
            for (int m = 0; m < 4; m++) {
                int r = wm * 64 + m * 16 + (lane & 15);
                int off = r * 128 + (cb ^ ((r & 7) << 4));
                ah[m] = *(const f16x8*)&lds[off];
                al[m] = *(const f16x8*)&lds[16384 + off];
            }
#pragma unroll
            for (int n = 0; n < 4; n++) {
                int r = wn * 64 + n * 16 + (lane & 15);
                int off = r * 128 + (cb ^ ((r & 7) << 4));
                bh[n] = *(const f16x8*)&lds[32768 + off];
                bl[n] = *(const f16x8*)&lds[49152 + off];
            }
#pragma unroll
            for (int m = 0; m < 4; m++)
#pragma unroll
                for (int n = 0; n < 4; n++) {
                    acc[m][n] = __builtin_amdgcn_mfma_f32_16x16x32_f16(ah[m], bh[n], acc[m][n], 0, 0, 0);
                    acc[m][n] = __builtin_amdgcn_mfma_f32_16x16x32_f16(ah[m], bl[n], acc[m][n], 0, 0, 0);
                    acc[m][n] = __builtin_amdgcn_mfma_f32_16x16x32_f16(al[m], bh[n], acc[m][n], 0, 0, 0);
                }
        }
        __syncthreads();   // all waves done reading before next overwrite
    }

    // epilogue: d = ||e||^2 - 2 S; per-row min with index; atomicMin merge
    float en[4];
    int colb = bn * 128 + wn * 64 + (lane & 15);
#pragma unroll
    for (int n = 0; n < 4; n++) en[n] = enorms[colb + n * 16];
#pragma unroll
    for (int m = 0; m < 4; m++) {
#pragma unroll
        for (int reg = 0; reg < 4; reg++) {
            float best = 3.4e38f;
            int bcol = 0x7fffffff;
#pragma unroll
            for (int n = 0; n < 4; n++) {
                float d = en[n] - 2.0f * acc[m][n][reg];
                int col = colb + n * 16;
                if (d < best) { best = d; bcol = col; }
            }
#pragma unroll
            for (int msk = 1; msk < 16; msk <<= 1) {
                float od = __shfl_xor(best, msk, 64);
                int oc = __shfl_xor(bcol, msk, 64);
                if (od < best || (od == best && oc < bcol)) { best = od; bcol = oc; }
            }
            if ((lane & 15) == 0) {
                int rowg = bm * 128 + wm * 64 + m * 16 + ((lane >> 4) << 2) + reg;
                unsigned bbits = __float_as_uint(best);
                unsigned key = (bbits & 0x80000000u) ? ~bbits : (bbits | 0x80000000u);
                atomicMin(&slots[rowg], ((u64)key << 32) | (unsigned)bcol);
            }
        }
    }
}

// ---------------------------------------------------------------------------
__global__ __launch_bounds__(256) void k_idx(const u64* __restrict__ slots,
                                             float* __restrict__ o_idx,
                                             int* __restrict__ counts) {
    int i = blockIdx.x * 256 + threadIdx.x;
    int idx = (int)(unsigned)(slots[i] & 0xFFFFFFFFULL);
    o_idx[i] = (float)idx;
    atomicAdd(&counts[idx], 1);
}

// ---------------------------------------------------------------------------
__global__ __launch_bounds__(1024) void k_cs(const int* __restrict__ counts,
                                             const float* __restrict__ ema_cs,
                                             float* __restrict__ o_ncs,
                                             float* __restrict__ o_perp) {
    __shared__ float red[1024];
    int t = threadIdx.x;
    float pre[8];
    float psum = 0.f, esum = 0.f;
#pragma unroll
    for (int k = 0; k < 8; k++) {
        int j = t * 8 + k;
        float c = (float)counts[j];
        float p = ema_cs[j] * 0.99f + 0.01f * c;
        pre[k] = p;
        psum += p;
        float ap = c * (1.0f / 8192.0f);
        esum += ap * logf(ap + 1e-10f);
    }
    red[t] = psum;
    __syncthreads();
    for (int off = 512; off > 0; off >>= 1) {
        if (t < off) red[t] += red[t + off];
        __syncthreads();
    }
    float n = red[0];
    __syncthreads();
    red[t] = esum;
    __syncthreads();
    for (int off = 512; off > 0; off >>= 1) {
        if (t < off) red[t] += red[t + off];
        __syncthreads();
    }
    if (t == 0) o_perp[0] = expf(-red[0]);
    float scale = n / (n + (float)VOCAB * 1e-5f);
#pragma unroll
    for (int k = 0; k < 8; k++) {
        int j = t * 8 + k;
        o_ncs[j] = (pre[k] + 1e-5f) * scale;
    }
}

// ---------------------------------------------------------------------------
__global__ __launch_bounds__(256) void k_gather(const float* __restrict__ embedding,
                                                const float* __restrict__ inputs,
                                                const float* __restrict__ o_idx,
                                                float* __restrict__ o_quant,
                                                float* __restrict__ partials) {
    int i = blockIdx.x, t = threadIdx.x;
    int idx = (int)o_idx[i];
    const float* erow = embedding + (size_t)idx * DIM;
    const float* xrow = inputs + (size_t)i * DIM;
    float* qrow = o_quant + (size_t)i * DIM;   // base offset 1 elem -> dword stores
    float acc = 0.f;
#pragma unroll
    for (int k = 0; k < 16; k++) {
        int d = t + 256 * k;
        float q = erow[d];
        qrow[d] = q;
        float df = q - xrow[d];
        acc += df * df;
    }
    __shared__ float red[256];
    red[t] = acc;
    __syncthreads();
    for (int off = 128; off > 0; off >>= 1) {
        if (t < off) red[t] += red[t + off];
        __syncthreads();
    }
    if (t == 0) partials[i] = red[0];
}

// ---------------------------------------------------------------------------
__global__ __launch_bounds__(1024) void k_loss(const float* __restrict__ partials,
                                               float* __restrict__ o_loss) {
    __shared__ float red[1024];
    int t = threadIdx.x;
    float s = 0.f;
#pragma unroll
    for (int k = 0; k < 8; k++) s += partials[t * 8 + k];
    red[t] = s;
    __syncthreads();
    for (int off = 512; off > 0; off >>= 1) {
        if (t < off) red[t] += red[t + off];
        __syncthreads();
    }
    if (t == 0) o_loss[0] = 0.25f * red[0] / ((float)N_TOK * (float)DIM);
}

// ---------------------------------------------------------------------------
// K_ema: block j owns code j. Build the ordered token list (deterministic),
// then new_ema_w = 0.99*ema_w + 0.01*sum(x), new_embedding = new_ema_w / ncs.
__global__ __launch_bounds__(256) void k_ema(const float* __restrict__ o_idx,
                                             const float* __restrict__ inputs,
                                             const float* __restrict__ ema_w,
                                             const float* __restrict__ o_ncs,
                                             float* __restrict__ o_neww,
                                             float* __restrict__ o_newemb) {
    int j = blockIdx.x, t = threadIdx.x;
    __shared__ int scan[256];
    __shared__ int list[256];
    __shared__ int s_total;
    int c = 0;
    for (int k = 0; k < 32; k++) {
        int tok = t * 32 + k;
        if ((int)o_idx[tok] == j) c++;
    }
    scan[t] = c;
    __syncthreads();
    for (int off = 1; off < 256; off <<= 1) {
        int add = (t >= off) ? scan[t - off] : 0;
        __syncthreads();
        scan[t] += add;
        __syncthreads();
    }
    int excl = scan[t] - c;
    if (t == 255) s_total = scan[255];
    __syncthreads();
    int pos = excl;
    for (int k = 0; k < 32; k++) {
        int tok = t * 32 + k;
        if ((int)o_idx[tok] == j && pos < 256) list[pos++] = tok;
    }
    __syncthreads();
    int total = s_total;
    float nc = o_ncs[j];
    size_t rowoff = (size_t)j * DIM;
#pragma unroll
    for (int k = 0; k < 16; k++) {
        int d = t + 256 * k;
        float s = 0.f;
        for (int q = 0; q < total; q++) s += inputs[(size_t)list[q] * DIM + d];
        float w = ema_w[rowoff + d] * 0.99f + 0.01f * s;
        o_neww[rowoff + d] = w;
        o_newemb[rowoff + d] = w / nc;
    }
}

// ---------------------------------------------------------------------------
extern "C" void kernel_launch(void* const* d_in, const int* in_sizes, int n_in,
                              void* d_out, int out_size, void* d_ws, size_t ws_size,
                              hipStream_t stream) {
    const float* inputs    = (const float*)d_in[0];
    const float* embedding = (const float*)d_in[1];
    const float* ema_w     = (const float*)d_in[2];
    const float* ema_cs    = (const float*)d_in[3];

    float* out = (float*)d_out;
    char* base = (char*)d_out;

    // scratch carved from d_out (lifetimes verified: all dead before the
    // kernel that overwrites their region runs)
    f16* apk       = (f16*)(base);                     // [0, 134217728)
    f16* bpk       = (f16*)(base + 134217728);         // [134217728, 268435456)
    float* enorms  = (float*)(base + 268435456);       // 32 KB (dead after gemm)
    u64* slots     = (u64*)(base + 268468224);         // 64 KB (dead after idx)
    int* counts    = (int*)(base + 268533760);         // 32 KB (dead after cs)
    float* partials= (float*)(base + 268566528);       // 32 KB (dead after loss)

    // output regions (element offsets in return order)
    float* o_loss   = out;                 // [1]
    float* o_quant  = out + 1;             // [8192*4096]
    float* o_perp   = out + 33554433;      // [1]
    float* o_idx    = out + 33554434;      // [8192]
    float* o_ncs    = out + 33562626;      // [8192]
    float* o_neww   = out + 33570818;      // [8192*4096]
    float* o_newemb = out + 67125250;      // [8192*4096]

    k_pack<<<dim3(N_TOK + VOCAB), dim3(256), 0, stream>>>(inputs, embedding, apk, bpk,
                                                          enorms, slots, counts);
    k_gemm<<<dim3(4096), dim3(256), 0, stream>>>(apk, bpk, enorms, slots);
    k_idx<<<dim3(32), dim3(256), 0, stream>>>(slots, o_idx, counts);
    k_cs<<<dim3(1), dim3(1024), 0, stream>>>(counts, ema_cs, o_ncs, o_perp);
    k_gather<<<dim3(N_TOK), dim3(256), 0, stream>>>(embedding, inputs, o_idx, o_quant, partials);
    k_loss<<<dim3(1), dim3(1024), 0, stream>>>(partials, o_loss);
    k_ema<<<dim3(VOCAB), dim3(256), 0, stream>>>(o_idx, inputs, ema_w, o_ncs, o_neww, o_newemb);
}

// Round 2
// 1931.652 us; speedup vs baseline: 1.2296x; 1.2296x over previous
//
#include <hip/hip_runtime.h>
#include <hip/hip_fp16.h>
#include <stdint.h>

typedef _Float16 f16;
typedef _Float16 f16x4 __attribute__((ext_vector_type(4)));
typedef _Float16 f16x8 __attribute__((ext_vector_type(8)));
typedef float f32x4 __attribute__((ext_vector_type(4)));
typedef unsigned long long u64;

#define N_TOK 8192
#define VOCAB 8192
#define DIM   4096
#define DELTA 1.5f

// ---------------------------------------------------------------------------
__device__ __forceinline__ void gload16(const f16* g, void* l) {
    __builtin_amdgcn_global_load_lds(
        (const __attribute__((address_space(1))) unsigned int*)(uintptr_t)g,
        (__attribute__((address_space(3))) unsigned int*)(uintptr_t)l,
        16, 0, 0);
}

__device__ __forceinline__ float keyinv(unsigned k) {
    unsigned b = (k & 0x80000000u) ? (k ^ 0x80000000u) : ~k;
    return __uint_as_float(b);
}

__device__ __forceinline__ void ins2(u64& k1, u64& k2, u64 v) {
    if (v < k1) { k2 = k1; k1 = v; }
    else if (v < k2) { k2 = v; }
}

// ---------------------------------------------------------------------------
// K_pack: fp16 hi-plane of inputs/embedding; embedding norms (f64 acc); zero counts.
__global__ __launch_bounds__(256) void k_pack(const float* __restrict__ inputs,
                                              const float* __restrict__ embedding,
                                              f16* __restrict__ apk, f16* __restrict__ bpk,
                                              float* __restrict__ enorms,
                                              int* __restrict__ counts) {
    int b = blockIdx.x, t = threadIdx.x;
    bool isB = b >= N_TOK;
    int row = isB ? b - N_TOK : b;
    const float* src = (isB ? embedding : inputs) + (size_t)row * DIM;
    f16* dst = (isB ? bpk : apk) + (size_t)row * DIM;
    double nrm = 0.0;
#pragma unroll
    for (int k = 0; k < 4; k++) {
        int d0 = t * 4 + 1024 * k;
        float4 v = *(const float4*)(src + d0);
        float xs[4] = {v.x, v.y, v.z, v.w};
        f16x4 hv;
#pragma unroll
        for (int u = 0; u < 4; u++) {
            hv[u] = (f16)xs[u];
            nrm += (double)xs[u] * (double)xs[u];
        }
        *(f16x4*)(dst + d0) = hv;
    }
    if (isB) {
        __shared__ double red[256];
        red[t] = nrm;
        __syncthreads();
        for (int off = 128; off > 0; off >>= 1) {
            if (t < off) red[t] += red[t + off];
            __syncthreads();
        }
        if (t == 0) {
            enorms[row] = (float)red[0];
            counts[row] = 0;
        }
    }
}

// ---------------------------------------------------------------------------
// K_gemm: approx S = x·e (hi-only fp16 MFMA), 128x128 tile, BK=64, 4 waves,
// 2-phase double-buffered staging (stage-next || compute-cur, 1 barrier/step).
// Epilogue stores per (row, 64-col slice) the 2 smallest (key|col) u64 pairs.
__global__ __launch_bounds__(256) void k_gemm(const f16* __restrict__ apk,
                                              const f16* __restrict__ bpk,
                                              const float* __restrict__ enorms,
                                              u64* __restrict__ cand) {
    __shared__ alignas(16) char lds[65536];   // 2 buffers x (A 16K | B 16K)
    int wg = blockIdx.x;
    wg = (wg & 7) * 512 + (wg >> 3);          // XCD swizzle (4096 % 8 == 0)
    int bm = wg >> 6, bn = wg & 63;
    int tid = threadIdx.x;
    int lane = tid & 63, wid = tid >> 6;
    int wm = wid >> 1, wn = wid & 1;

    // staging: 8 issues/thread/K-step; pre-swizzled global source, linear LDS dest
    const f16* srcs[8];
    unsigned lof[8];
#pragma unroll
    for (int e = 0; e < 8; e++) {
        int tile = e >> 2, q = e & 3;
        int s = (q * 4 + wid) * 64 + lane;     // 16B slot 0..1023 within tile
        int r = s >> 3;                        // row 0..127
        int c8 = (s & 7) ^ (r & 7);            // inverse swizzle on source
        int row = (tile ? bn : bm) * 128 + r;
        srcs[e] = (tile ? bpk : apk) + (size_t)row * DIM + c8 * 8;
        lof[e] = tile * 16384 + (q * 4 + wid) * 1024;   // + lane*16 by HW
    }

    f32x4 acc[4][4];
#pragma unroll
    for (int m = 0; m < 4; m++)
#pragma unroll
        for (int n = 0; n < 4; n++) acc[m][n] = (f32x4){0.f, 0.f, 0.f, 0.f};

    // prologue: stage kt=0 into buffer 0
#pragma unroll
    for (int e = 0; e < 8; e++) { gload16(srcs[e], &lds[lof[e]]); srcs[e] += 64; }
    __syncthreads();

    for (int kt = 0; kt < 64; ++kt) {
        unsigned cb = (kt & 1) ? 32768u : 0u;
        if (kt < 63) {
#pragma unroll
            for (int e = 0; e < 8; e++) { gload16(srcs[e], &lds[(cb ^ 32768u) + lof[e]]); srcs[e] += 64; }
        }
#pragma unroll
        for (int kk = 0; kk < 2; kk++) {
            f16x8 ah[4], bh[4];
            int cbyte = kk * 64 + (lane >> 4) * 16;
#pragma unroll
            for (int m = 0; m < 4; m++) {
                int r = wm * 64 + m * 16 + (lane & 15);
                ah[m] = *(const f16x8*)&lds[cb + r * 128 + (cbyte ^ ((r & 7) << 4))];
            }
#pragma unroll
            for (int n = 0; n < 4; n++) {
                int r = wn * 64 + n * 16 + (lane & 15);
                bh[n] = *(const f16x8*)&lds[cb + 16384 + r * 128 + (cbyte ^ ((r & 7) << 4))];
            }
#pragma unroll
            for (int m = 0; m < 4; m++)
#pragma unroll
                for (int n = 0; n < 4; n++)
                    acc[m][n] = __builtin_amdgcn_mfma_f32_16x16x32_f16(ah[m], bh[n], acc[m][n], 0, 0, 0);
        }
        __syncthreads();   // drains stage (vmcnt) + joins readers before overwrite
    }

    // epilogue: approx dist = ||e||^2 - 2S; keep 2 smallest per (row, 64-col slice)
    float en[4];
    int colb = bn * 128 + wn * 64 + (lane & 15);
#pragma unroll
    for (int n = 0; n < 4; n++) en[n] = enorms[colb + n * 16];
#pragma unroll
    for (int m = 0; m < 4; m++) {
#pragma unroll
        for (int reg = 0; reg < 4; reg++) {
            u64 k1 = ~0ull, k2 = ~0ull;
#pragma unroll
            for (int n = 0; n < 4; n++) {
                float d = en[n] - 2.0f * acc[m][n][reg];
                unsigned b = __float_as_uint(d);
                unsigned key = (b & 0x80000000u) ? ~b : (b | 0x80000000u);
                ins2(k1, k2, ((u64)key << 32) | (unsigned)(colb + n * 16));
            }
#pragma unroll
            for (int msk = 1; msk < 16; msk <<= 1) {
                u64 o1 = __shfl_xor(k1, msk, 64);
                u64 o2 = __shfl_xor(k2, msk, 64);
                ins2(k1, k2, o1);
                ins2(k1, k2, o2);
            }
            if ((lane & 15) == 0) {
                int rowg = bm * 128 + wm * 64 + m * 16 + ((lane >> 4) << 2) + reg;
                size_t slot = ((size_t)rowg * 64 + bn) * 2 + wn;
                ulonglong2 v; v.x = k1; v.y = k2;
                *(ulonglong2*)&cand[slot * 2] = v;
            }
        }
    }
}

// ---------------------------------------------------------------------------
// K_cand: per token, min over 256 stored entries; collect candidates within
// DELTA; exact f32 recheck; fused quantize-copy + loss partial + count.
__global__ __launch_bounds__(256) void k_cand(const u64* __restrict__ cand,
                                              const float* __restrict__ enorms,
                                              const float* __restrict__ inputs,
                                              const float* __restrict__ embedding,
                                              float* __restrict__ o_idx,
                                              float* __restrict__ o_quant,
                                              float* __restrict__ partials,
                                              int* __restrict__ counts) {
    int tok = blockIdx.x, t = threadIdx.x;
    __shared__ u64 redu[256];
    __shared__ float redf[256];
    __shared__ int clist[64];
    __shared__ int s_cnt;
    u64 e = cand[(size_t)tok * 256 + t];
    redu[t] = e;
    __syncthreads();
    for (int off = 128; off > 0; off >>= 1) {
        if (t < off) { u64 o = redu[t + off]; if (o < redu[t]) redu[t] = o; }
        __syncthreads();
    }
    float dmin = keyinv((unsigned)(redu[0] >> 32));
    if (t == 0) s_cnt = 0;
    __syncthreads();
    float myd = keyinv((unsigned)(e >> 32));
    if (myd <= dmin + DELTA) {
        int p = atomicAdd(&s_cnt, 1);
        if (p < 64) clist[p] = (int)(unsigned)(e & 0xffffffffu);
    }
    __syncthreads();
    int nc = min(s_cnt, 64);

    const float* xrow = inputs + (size_t)tok * DIM;
    float xr[16];
#pragma unroll
    for (int k = 0; k < 16; k++) xr[k] = xrow[t + 256 * k];

    float best = 3.4e38f;
    int bcol = 0x7fffffff;
    for (int i = 0; i < nc; i++) {
        int c = clist[i];
        const float* erow = embedding + (size_t)c * DIM;
        float p = 0.f;
#pragma unroll
        for (int k = 0; k < 16; k++) p += xr[k] * erow[t + 256 * k];
        redf[t] = p;
        __syncthreads();
        for (int off = 128; off > 0; off >>= 1) {
            if (t < off) redf[t] += redf[t + off];
            __syncthreads();
        }
        float dist = enorms[c] - 2.0f * redf[0];
        __syncthreads();
        if (dist < best || (dist == best && c < bcol)) { best = dist; bcol = c; }
    }
    // all threads agree on bcol (reduced values identical)
    const float* eb = embedding + (size_t)bcol * DIM;
    float* qrow = o_quant + (size_t)tok * DIM;
    float ls = 0.f;
#pragma unroll
    for (int k = 0; k < 16; k++) {
        int d = t + 256 * k;
        float q = eb[d];
        qrow[d] = q;
        float df = q - xr[k];
        ls += df * df;
    }
    redf[t] = ls;
    __syncthreads();
    for (int off = 128; off > 0; off >>= 1) {
        if (t < off) redf[t] += redf[t + off];
        __syncthreads();
    }
    if (t == 0) {
        partials[tok] = redf[0];
        o_idx[tok] = (float)bcol;
        atomicAdd(&counts[bcol], 1);
    }
}

// ---------------------------------------------------------------------------
__global__ __launch_bounds__(1024) void k_cs(const int* __restrict__ counts,
                                             const float* __restrict__ ema_cs,
                                             float* __restrict__ o_ncs,
                                             float* __restrict__ o_perp) {
    __shared__ float red[1024];
    int t = threadIdx.x;
    float pre[8];
    float psum = 0.f, esum = 0.f;
#pragma unroll
    for (int k = 0; k < 8; k++) {
        int j = t * 8 + k;
        float c = (float)counts[j];
        float p = ema_cs[j] * 0.99f + 0.01f * c;
        pre[k] = p;
        psum += p;
        float ap = c * (1.0f / 8192.0f);
        esum += ap * logf(ap + 1e-10f);
    }
    red[t] = psum;
    __syncthreads();
    for (int off = 512; off > 0; off >>= 1) {
        if (t < off) red[t] += red[t + off];
        __syncthreads();
    }
    float n = red[0];
    __syncthreads();
    red[t] = esum;
    __syncthreads();
    for (int off = 512; off > 0; off >>= 1) {
        if (t < off) red[t] += red[t + off];
        __syncthreads();
    }
    if (t == 0) o_perp[0] = expf(-red[0]);
    float scale = n / (n + (float)VOCAB * 1e-5f);
#pragma unroll
    for (int k = 0; k < 8; k++) {
        int j = t * 8 + k;
        o_ncs[j] = (pre[k] + 1e-5f) * scale;
    }
}

// ---------------------------------------------------------------------------
__global__ __launch_bounds__(1024) void k_loss(const float* __restrict__ partials,
                                               float* __restrict__ o_loss) {
    __shared__ float red[1024];
    int t = threadIdx.x;
    float s = 0.f;
#pragma unroll
    for (int k = 0; k < 8; k++) s += partials[t * 8 + k];
    red[t] = s;
    __syncthreads();
    for (int off = 512; off > 0; off >>= 1) {
        if (t < off) red[t] += red[t + off];
        __syncthreads();
    }
    if (t == 0) o_loss[0] = 0.25f * red[0] / ((float)N_TOK * (float)DIM);
}

// ---------------------------------------------------------------------------
// K_ema: block j owns code j; ordered token list (deterministic) then EMA math.
__global__ __launch_bounds__(256) void k_ema(const float* __restrict__ o_idx,
                                             const float* __restrict__ inputs,
                                             const float* __restrict__ ema_w,
                                             const float* __restrict__ o_ncs,
                                             float* __restrict__ o_neww,
                                             float* __restrict__ o_newemb) {
    int j = blockIdx.x, t = threadIdx.x;
    __shared__ int scan[256];
    __shared__ int list[256];
    __shared__ int s_total;
    int c = 0;
    for (int k = 0; k < 32; k++) {
        int tok = t * 32 + k;
        if ((int)o_idx[tok] == j) c++;
    }
    scan[t] = c;
    __syncthreads();
    for (int off = 1; off < 256; off <<= 1) {
        int add = (t >= off) ? scan[t - off] : 0;
        __syncthreads();
        scan[t] += add;
        __syncthreads();
    }
    int excl = scan[t] - c;
    if (t == 255) s_total = scan[255];
    __syncthreads();
    int pos = excl;
    for (int k = 0; k < 32; k++) {
        int tok = t * 32 + k;
        if ((int)o_idx[tok] == j && pos < 256) list[pos++] = tok;
    }
    __syncthreads();
    int total = s_total;
    float nc = o_ncs[j];
    size_t rowoff = (size_t)j * DIM;
#pragma unroll
    for (int k = 0; k < 16; k++) {
        int d = t + 256 * k;
        float s = 0.f;
        for (int q = 0; q < total; q++) s += inputs[(size_t)list[q] * DIM + d];
        float w = ema_w[rowoff + d] * 0.99f + 0.01f * s;
        o_neww[rowoff + d] = w;
        o_newemb[rowoff + d] = w / nc;
    }
}

// ---------------------------------------------------------------------------
extern "C" void kernel_launch(void* const* d_in, const int* in_sizes, int n_in,
                              void* d_out, int out_size, void* d_ws, size_t ws_size,
                              hipStream_t stream) {
    const float* inputs    = (const float*)d_in[0];
    const float* embedding = (const float*)d_in[1];
    const float* ema_w     = (const float*)d_in[2];
    const float* ema_cs    = (const float*)d_in[3];

    float* out = (float*)d_out;
    char* base = (char*)d_out;

    // scratch carved from d_out (lifetime-checked):
    // apk/bpk [0,128M) dead after k_gemm (outputs there written by k_cand+)
    // cand/enorms/counts/partials parked inside o_neww region (written only by k_ema, last)
    f16* apk        = (f16*)(base);                    // [0, 64M)
    f16* bpk        = (f16*)(base + 67108864);         // [64M, 128M)
    u64* cand       = (u64*)(base + 167772160);        // 16 MB, dead after k_cand
    float* enorms   = (float*)(base + 184549376);      // 32 KB, dead after k_cand
    int* counts     = (int*)(base + 184582144);        // 32 KB, dead after k_cs
    float* partials = (float*)(base + 184614912);      // 32 KB, dead after k_loss

    // output regions (element offsets, return order)
    float* o_loss   = out;                 // [1]
    float* o_quant  = out + 1;             // [8192*4096]
    float* o_perp   = out + 33554433;      // [1]
    float* o_idx    = out + 33554434;      // [8192]
    float* o_ncs    = out + 33562626;      // [8192]
    float* o_neww   = out + 33570818;      // [8192*4096]
    float* o_newemb = out + 67125250;      // [8192*4096]

    k_pack<<<dim3(N_TOK + VOCAB), dim3(256), 0, stream>>>(inputs, embedding, apk, bpk,
                                                          enorms, counts);
    k_gemm<<<dim3(4096), dim3(256), 0, stream>>>(apk, bpk, enorms, cand);
    k_cand<<<dim3(N_TOK), dim3(256), 0, stream>>>(cand, enorms, inputs, embedding,
                                                  o_idx, o_quant, partials, counts);
    k_cs<<<dim3(1), dim3(1024), 0, stream>>>(counts, ema_cs, o_ncs, o_perp);
    k_loss<<<dim3(1), dim3(1024), 0, stream>>>(partials, o_loss);
    k_ema<<<dim3(VOCAB), dim3(256), 0, stream>>>(o_idx, inputs, ema_w, o_ncs, o_neww, o_newemb);
}

// Round 3
// 1843.387 us; speedup vs baseline: 1.2885x; 1.0479x over previous
//
#include <hip/hip_runtime.h>
#include <hip/hip_fp16.h>
#include <stdint.h>

typedef _Float16 f16;
typedef _Float16 f16x4 __attribute__((ext_vector_type(4)));
typedef _Float16 f16x8 __attribute__((ext_vector_type(8)));
typedef float f32x4 __attribute__((ext_vector_type(4)));
typedef unsigned long long u64;

#define N_TOK 8192
#define VOCAB 8192
#define DIM   4096
#define DELTA 1.5f

// ---------------------------------------------------------------------------
__device__ __forceinline__ void gload16(const f16* g, void* l) {
    __builtin_amdgcn_global_load_lds(
        (const __attribute__((address_space(1))) unsigned int*)(uintptr_t)g,
        (__attribute__((address_space(3))) unsigned int*)(uintptr_t)l,
        16, 0, 0);
}

__device__ __forceinline__ float keyinv(unsigned k) {
    unsigned b = (k & 0x80000000u) ? (k ^ 0x80000000u) : ~k;
    return __uint_as_float(b);
}

__device__ __forceinline__ void ins2(u64& k1, u64& k2, u64 v) {
    if (v < k1) { k2 = k1; k1 = v; }
    else if (v < k2) { k2 = v; }
}

// ---------------------------------------------------------------------------
// K_pack: fp16 hi-plane of inputs/embedding; embedding norms (f64 acc); zero counts.
__global__ __launch_bounds__(256) void k_pack(const float* __restrict__ inputs,
                                              const float* __restrict__ embedding,
                                              f16* __restrict__ apk, f16* __restrict__ bpk,
                                              float* __restrict__ enorms,
                                              int* __restrict__ counts) {
    int b = blockIdx.x, t = threadIdx.x;
    bool isB = b >= N_TOK;
    int row = isB ? b - N_TOK : b;
    const float* src = (isB ? embedding : inputs) + (size_t)row * DIM;
    f16* dst = (isB ? bpk : apk) + (size_t)row * DIM;
    double nrm = 0.0;
#pragma unroll
    for (int k = 0; k < 4; k++) {
        int d0 = t * 4 + 1024 * k;
        float4 v = *(const float4*)(src + d0);
        float xs[4] = {v.x, v.y, v.z, v.w};
        f16x4 hv;
#pragma unroll
        for (int u = 0; u < 4; u++) {
            hv[u] = (f16)xs[u];
            nrm += (double)xs[u] * (double)xs[u];
        }
        *(f16x4*)(dst + d0) = hv;
    }
    if (isB) {
        __shared__ double red[256];
        red[t] = nrm;
        __syncthreads();
        for (int off = 128; off > 0; off >>= 1) {
            if (t < off) red[t] += red[t + off];
            __syncthreads();
        }
        if (t == 0) {
            enorms[row] = (float)red[0];
            counts[row] = 0;
        }
    }
}

// ---------------------------------------------------------------------------
// K_gemm: approx S = x·e (hi-only fp16 MFMA). 256x256 tile, BK=64, 8 waves
// (2Mx4N), 512 thr, 128KB LDS (2 K-tile dbuf), 4-phase/K-tile schedule:
// raw s_barrier + lgkmcnt(0)+sched_barrier + setprio around 16-MFMA clusters;
// all 8 stage loads for tile t+1 issue in phase 0 (vmcnt(0) 3 phases later).
// Epilogue stores per (row, 64-col slice) the 2 smallest (key|col) u64 pairs.
__global__ __launch_bounds__(512) void k_gemm(const f16* __restrict__ apk,
                                              const f16* __restrict__ bpk,
                                              const float* __restrict__ enorms,
                                              u64* __restrict__ cand) {
    extern __shared__ char lds[];             // 131072 bytes at launch
    int wg = blockIdx.x;
    wg = (wg & 7) * 128 + (wg >> 3);          // XCD swizzle (1024 % 8 == 0)
    int bm = wg >> 5, bn = wg & 31;
    int tid = threadIdx.x;
    int lane = tid & 63, wid = tid >> 6;
    int wm = wid >> 2, wn = wid & 3;          // 2 x 4 wave grid, wave owns 128x64

    // staging: 4 A-issues/thread/K-tile (+4 B via uniform delta), pre-swizzled src
    const f16* srcs[4];
    unsigned lofA[4];
#pragma unroll
    for (int j = 0; j < 4; j++) {
        int s = j * 512 + tid;                // 16B slot 0..2047 within A tile
        int r = s >> 3;                       // row 0..255
        int c8 = (s & 7) ^ (r & 7);           // inverse swizzle on source
        srcs[j] = apk + (size_t)(bm * 256 + r) * DIM + c8 * 8;
        lofA[j] = j * 8192 + wid * 1024;      // + lane*16 by HW
    }
    const ptrdiff_t bdelta = (bpk + (size_t)bn * 256 * DIM) - (apk + (size_t)bm * 256 * DIM);

    // LDS read bases (XOR swizzle constant per lane: rows differ by mult of 8)
    const int xm = (lane & 7) << 4;
    const int cks0 = ((lane >> 4) * 16) ^ xm;
    const int cks1 = ((lane >> 4) * 16 + 64) ^ xm;
    const int abase = (wm * 128 + (lane & 15)) * 128;
    const int bbase = 32768 + (wn * 64 + (lane & 15)) * 128;

    f32x4 acc[8][4];
#pragma unroll
    for (int m = 0; m < 8; m++)
#pragma unroll
        for (int n = 0; n < 4; n++) acc[m][n] = (f32x4){0.f, 0.f, 0.f, 0.f};
    f16x8 a[4][2], b0[2][2], b1[2][2];

#define STAGE(buf) { _Pragma("unroll") for (int j = 0; j < 4; j++) { \
        gload16(srcs[j], &lds[(buf) * 65536 + lofA[j]]); \
        gload16(srcs[j] + bdelta, &lds[(buf) * 65536 + 32768 + lofA[j]]); \
        srcs[j] += 64; } }
#define LDA(mh) { _Pragma("unroll") for (int m = 0; m < 4; m++) { \
        a[m][0] = *(const f16x8*)&lds[curoff + abase + ((mh) * 64 + m * 16) * 128 + cks0]; \
        a[m][1] = *(const f16x8*)&lds[curoff + abase + ((mh) * 64 + m * 16) * 128 + cks1]; } }
#define LDB(bb, nh) { _Pragma("unroll") for (int n = 0; n < 2; n++) { \
        bb[n][0] = *(const f16x8*)&lds[curoff + bbase + ((nh) * 32 + n * 16) * 128 + cks0]; \
        bb[n][1] = *(const f16x8*)&lds[curoff + bbase + ((nh) * 32 + n * 16) * 128 + cks1]; } }
#define QUAD(mh, nh, bb) { _Pragma("unroll") for (int m = 0; m < 4; m++) \
        _Pragma("unroll") for (int n = 0; n < 2; n++) \
        _Pragma("unroll") for (int ks = 0; ks < 2; ks++) \
        acc[(mh) * 4 + m][(nh) * 2 + n] = __builtin_amdgcn_mfma_f32_16x16x32_f16( \
            a[m][ks], bb[n][ks], acc[(mh) * 4 + m][(nh) * 2 + n], 0, 0, 0); }
#define BAR() __builtin_amdgcn_s_barrier()
#define LGKM0() { asm volatile("s_waitcnt lgkmcnt(0)" ::: "memory"); __builtin_amdgcn_sched_barrier(0); }

    STAGE(0);              // prologue: tile 0 -> buf 0
    __syncthreads();       // full drain once

    for (int kt = 0; kt < 64; ++kt) {
        const unsigned curoff = (kt & 1) ? 65536u : 0u;
        // phase 0: quad(0,0); issue ALL next-tile stages (wait is 3 phases away)
        LDA(0); LDB(b0, 0);
        if (kt < 63) STAGE((kt & 1) ^ 1);
        BAR(); LGKM0();
        __builtin_amdgcn_s_setprio(1); QUAD(0, 0, b0); __builtin_amdgcn_s_setprio(0);
        BAR();
        // phase 1: quad(0,1)
        LDB(b1, 1);
        BAR(); LGKM0();
        __builtin_amdgcn_s_setprio(1); QUAD(0, 1, b1); __builtin_amdgcn_s_setprio(0);
        BAR();
        // phase 2: quad(1,0) (reuses b0)
        LDA(1);
        BAR(); LGKM0();
        __builtin_amdgcn_s_setprio(1); QUAD(1, 0, b0); __builtin_amdgcn_s_setprio(0);
        BAR();
        // phase 3: quad(1,1) (reuses a, b1); then join stages for next tile
        __builtin_amdgcn_s_setprio(1); QUAD(1, 1, b1); __builtin_amdgcn_s_setprio(0);
        asm volatile("s_waitcnt vmcnt(0)" ::: "memory");
        BAR();
    }

    // epilogue: approx dist = ||e||^2 - 2S; top-2 per (row, 64-col slice)
    float en[4];
    int colb = bn * 256 + wn * 64 + (lane & 15);
#pragma unroll
    for (int n = 0; n < 4; n++) en[n] = enorms[colb + n * 16];
#pragma unroll
    for (int M = 0; M < 8; M++) {
#pragma unroll
        for (int reg = 0; reg < 4; reg++) {
            u64 k1 = ~0ull, k2 = ~0ull;
#pragma unroll
            for (int n = 0; n < 4; n++) {
                float d = en[n] - 2.0f * acc[M][n][reg];
                unsigned b = __float_as_uint(d);
                unsigned key = (b & 0x80000000u) ? ~b : (b | 0x80000000u);
                ins2(k1, k2, ((u64)key << 32) | (unsigned)(colb + n * 16));
            }
#pragma unroll
            for (int msk = 1; msk < 16; msk <<= 1) {
                u64 o1 = __shfl_xor(k1, msk, 64);
                u64 o2 = __shfl_xor(k2, msk, 64);
                ins2(k1, k2, o1);
                ins2(k1, k2, o2);
            }
            if ((lane & 15) == 0) {
                int rowg = bm * 256 + wm * 128 + M * 16 + ((lane >> 4) << 2) + reg;
                size_t slot = ((size_t)rowg * 128 + bn * 4 + wn) * 2;
                ulonglong2 v; v.x = k1; v.y = k2;
                *(ulonglong2*)&cand[slot] = v;
            }
        }
    }
#undef STAGE
#undef LDA
#undef LDB
#undef QUAD
#undef BAR
#undef LGKM0
}

// ---------------------------------------------------------------------------
// K_cand: per token, min over 256 stored entries; collect candidates within
// DELTA; exact f32 recheck; fused quantize-copy + loss partial + count.
__global__ __launch_bounds__(256) void k_cand(const u64* __restrict__ cand,
                                              const float* __restrict__ enorms,
                                              const float* __restrict__ inputs,
                                              const float* __restrict__ embedding,
                                              float* __restrict__ o_idx,
                                              float* __restrict__ o_quant,
                                              float* __restrict__ partials,
                                              int* __restrict__ counts) {
    int tok = blockIdx.x, t = threadIdx.x;
    __shared__ u64 redu[256];
    __shared__ float redf[256];
    __shared__ int clist[64];
    __shared__ int s_cnt;
    u64 e = cand[(size_t)tok * 256 + t];
    redu[t] = e;
    __syncthreads();
    for (int off = 128; off > 0; off >>= 1) {
        if (t < off) { u64 o = redu[t + off]; if (o < redu[t]) redu[t] = o; }
        __syncthreads();
    }
    float dmin = keyinv((unsigned)(redu[0] >> 32));
    if (t == 0) s_cnt = 0;
    __syncthreads();
    float myd = keyinv((unsigned)(e >> 32));
    if (myd <= dmin + DELTA) {
        int p = atomicAdd(&s_cnt, 1);
        if (p < 64) clist[p] = (int)(unsigned)(e & 0xffffffffu);
    }
    __syncthreads();
    int nc = min(s_cnt, 64);

    const float* xrow = inputs + (size_t)tok * DIM;
    float xr[16];
#pragma unroll
    for (int k = 0; k < 16; k++) xr[k] = xrow[t + 256 * k];

    float best = 3.4e38f;
    int bcol = 0x7fffffff;
    for (int i = 0; i < nc; i++) {
        int c = clist[i];
        const float* erow = embedding + (size_t)c * DIM;
        float p = 0.f;
#pragma unroll
        for (int k = 0; k < 16; k++) p += xr[k] * erow[t + 256 * k];
        redf[t] = p;
        __syncthreads();
        for (int off = 128; off > 0; off >>= 1) {
            if (t < off) redf[t] += redf[t + off];
            __syncthreads();
        }
        float dist = enorms[c] - 2.0f * redf[0];
        __syncthreads();
        if (dist < best || (dist == best && c < bcol)) { best = dist; bcol = c; }
    }
    const float* eb = embedding + (size_t)bcol * DIM;
    float* qrow = o_quant + (size_t)tok * DIM;
    float ls = 0.f;
#pragma unroll
    for (int k = 0; k < 16; k++) {
        int d = t + 256 * k;
        float q = eb[d];
        qrow[d] = q;
        float df = q - xr[k];
        ls += df * df;
    }
    redf[t] = ls;
    __syncthreads();
    for (int off = 128; off > 0; off >>= 1) {
        if (t < off) redf[t] += redf[t + off];
        __syncthreads();
    }
    if (t == 0) {
        partials[tok] = redf[0];
        o_idx[tok] = (float)bcol;
        atomicAdd(&counts[bcol], 1);
    }
}

// ---------------------------------------------------------------------------
__global__ __launch_bounds__(1024) void k_cs(const int* __restrict__ counts,
                                             const float* __restrict__ ema_cs,
                                             float* __restrict__ o_ncs,
                                             float* __restrict__ o_perp) {
    __shared__ float red[1024];
    int t = threadIdx.x;
    float pre[8];
    float psum = 0.f, esum = 0.f;
#pragma unroll
    for (int k = 0; k < 8; k++) {
        int j = t * 8 + k;
        float c = (float)counts[j];
        float p = ema_cs[j] * 0.99f + 0.01f * c;
        pre[k] = p;
        psum += p;
        float ap = c * (1.0f / 8192.0f);
        esum += ap * logf(ap + 1e-10f);
    }
    red[t] = psum;
    __syncthreads();
    for (int off = 512; off > 0; off >>= 1) {
        if (t < off) red[t] += red[t + off];
        __syncthreads();
    }
    float n = red[0];
    __syncthreads();
    red[t] = esum;
    __syncthreads();
    for (int off = 512; off > 0; off >>= 1) {
        if (t < off) red[t] += red[t + off];
        __syncthreads();
    }
    if (t == 0) o_perp[0] = expf(-red[0]);
    float scale = n / (n + (float)VOCAB * 1e-5f);
#pragma unroll
    for (int k = 0; k < 8; k++) {
        int j = t * 8 + k;
        o_ncs[j] = (pre[k] + 1e-5f) * scale;
    }
}

// ---------------------------------------------------------------------------
__global__ __launch_bounds__(1024) void k_loss(const float* __restrict__ partials,
                                               float* __restrict__ o_loss) {
    __shared__ float red[1024];
    int t = threadIdx.x;
    float s = 0.f;
#pragma unroll
    for (int k = 0; k < 8; k++) s += partials[t * 8 + k];
    red[t] = s;
    __syncthreads();
    for (int off = 512; off > 0; off >>= 1) {
        if (t < off) red[t] += red[t + off];
        __syncthreads();
    }
    if (t == 0) o_loss[0] = 0.25f * red[0] / ((float)N_TOK * (float)DIM);
}

// ---------------------------------------------------------------------------
// K_ema: block j owns code j; ordered token list (deterministic) then EMA math.
__global__ __launch_bounds__(256) void k_ema(const float* __restrict__ o_idx,
                                             const float* __restrict__ inputs,
                                             const float* __restrict__ ema_w,
                                             const float* __restrict__ o_ncs,
                                             float* __restrict__ o_neww,
                                             float* __restrict__ o_newemb) {
    int j = blockIdx.x, t = threadIdx.x;
    __shared__ int scan[256];
    __shared__ int list[256];
    __shared__ int s_total;
    int c = 0;
    for (int k = 0; k < 32; k++) {
        int tok = t * 32 + k;
        if ((int)o_idx[tok] == j) c++;
    }
    scan[t] = c;
    __syncthreads();
    for (int off = 1; off < 256; off <<= 1) {
        int add = (t >= off) ? scan[t - off] : 0;
        __syncthreads();
        scan[t] += add;
        __syncthreads();
    }
    int excl = scan[t] - c;
    if (t == 255) s_total = scan[255];
    __syncthreads();
    int pos = excl;
    for (int k = 0; k < 32; k++) {
        int tok = t * 32 + k;
        if ((int)o_idx[tok] == j && pos < 256) list[pos++] = tok;
    }
    __syncthreads();
    int total = s_total;
    float nc = o_ncs[j];
    size_t rowoff = (size_t)j * DIM;
#pragma unroll
    for (int k = 0; k < 16; k++) {
        int d = t + 256 * k;
        float s = 0.f;
        for (int q = 0; q < total; q++) s += inputs[(size_t)list[q] * DIM + d];
        float w = ema_w[rowoff + d] * 0.99f + 0.01f * s;
        o_neww[rowoff + d] = w;
        o_newemb[rowoff + d] = w / nc;
    }
}

// ---------------------------------------------------------------------------
extern "C" void kernel_launch(void* const* d_in, const int* in_sizes, int n_in,
                              void* d_out, int out_size, void* d_ws, size_t ws_size,
                              hipStream_t stream) {
    const float* inputs    = (const float*)d_in[0];
    const float* embedding = (const float*)d_in[1];
    const float* ema_w     = (const float*)d_in[2];
    const float* ema_cs    = (const float*)d_in[3];

    float* out = (float*)d_out;
    char* base = (char*)d_out;

    // scratch carved from d_out (lifetime-checked, layout proven in round 2)
    f16* apk        = (f16*)(base);                    // [0, 64M)
    f16* bpk        = (f16*)(base + 67108864);         // [64M, 128M)
    u64* cand       = (u64*)(base + 167772160);        // 16 MB, dead after k_cand
    float* enorms   = (float*)(base + 184549376);      // 32 KB, dead after k_cand
    int* counts     = (int*)(base + 184582144);        // 32 KB, dead after k_cs
    float* partials = (float*)(base + 184614912);      // 32 KB, dead after k_loss

    // output regions (element offsets, return order)
    float* o_loss   = out;                 // [1]
    float* o_quant  = out + 1;             // [8192*4096]
    float* o_perp   = out + 33554433;      // [1]
    float* o_idx    = out + 33554434;      // [8192]
    float* o_ncs    = out + 33562626;      // [8192]
    float* o_neww   = out + 33570818;      // [8192*4096]
    float* o_newemb = out + 67125250;      // [8192*4096]

    k_pack<<<dim3(N_TOK + VOCAB), dim3(256), 0, stream>>>(inputs, embedding, apk, bpk,
                                                          enorms, counts);
    k_gemm<<<dim3(1024), dim3(512), 131072, stream>>>(apk, bpk, enorms, cand);
    k_cand<<<dim3(N_TOK), dim3(256), 0, stream>>>(cand, enorms, inputs, embedding,
                                                  o_idx, o_quant, partials, counts);
    k_cs<<<dim3(1), dim3(1024), 0, stream>>>(counts, ema_cs, o_ncs, o_perp);
    k_loss<<<dim3(1), dim3(1024), 0, stream>>>(partials, o_loss);
    k_ema<<<dim3(VOCAB), dim3(256), 0, stream>>>(o_idx, inputs, ema_w, o_ncs, o_neww, o_newemb);
}